// Round 1
// baseline (105.737 us; speedup 1.0000x reference)
//
#include <hip/hip_runtime.h>
#include <stdint.h>

#define N1     97
#define N1SQ   9409
#define NV3    912673      // 97^3 lattice vertices
#define RES    96
#define NCELL  884736      // 96^3 cells
#define VBLOCKS 892        // ceil(912673/1024)
#define CBLOCKS 864        // 884736/1024 exactly
#define UVN    2304
#define UVCELLS 5308416    // 2304^2
#define UVFLOATS 42467328  // UVCELLS*8

__device__ __constant__ int d_tt[16][6] = {
    {-1,-1,-1,-1,-1,-1}, {1,0,2,-1,-1,-1}, {4,0,3,-1,-1,-1}, {1,4,2,1,3,4},
    {3,1,5,-1,-1,-1}, {2,3,0,2,5,3}, {1,4,0,1,5,4}, {4,2,5,-1,-1,-1},
    {4,5,2,-1,-1,-1}, {4,1,0,4,5,1}, {3,2,0,3,5,2}, {1,3,5,-1,-1,-1},
    {4,1,2,4,3,1}, {3,0,4,-1,-1,-1}, {2,0,1,-1,-1,-1}, {-1,-1,-1,-1,-1,-1}};
__device__ __constant__ int d_ntri[16] = {0,1,1,2,1,2,2,1,1,2,2,1,2,1,1,0};
__device__ __constant__ int d_six[6][4] = {
    {0,5,1,7},{0,1,3,7},{0,3,2,7},{0,2,6,7},{0,6,4,7},{0,4,5,7}};
__device__ __constant__ int d_eb[6][2] = {{0,1},{0,2},{0,3},{1,2},{1,3},{2,3}};

__device__ __forceinline__ int corner_off(int b) {
    return (b >> 2) * N1SQ + ((b >> 1) & 1) * N1 + (b & 1);
}

// K1: per lattice vertex: 7-dir crossing mask + block-level exclusive scan of counts
__global__ __launch_bounds__(1024) void k_vscan(const float* __restrict__ sdf,
                                                uint8_t* __restrict__ mask,
                                                uint32_t* __restrict__ vloc,
                                                uint32_t* __restrict__ vsums) {
    int v = blockIdx.x * 1024 + threadIdx.x;
    uint32_t cnt = 0;
    uint32_t m = 0;
    if (v < NV3) {
        int x = v / N1SQ;
        int r = v - x * N1SQ;
        int y = r / N1;
        int z = r - y * N1;
        bool o0 = sdf[v] >= 0.f;
        bool bx = x < RES, by = y < RES, bz = z < RES;
        if (bz            && ((sdf[v + 1]    >= 0.f) != o0)) m |= 1u;
        if (by            && ((sdf[v + 97]   >= 0.f) != o0)) m |= 2u;
        if (by && bz      && ((sdf[v + 98]   >= 0.f) != o0)) m |= 4u;
        if (bx            && ((sdf[v + 9409] >= 0.f) != o0)) m |= 8u;
        if (bx && bz      && ((sdf[v + 9410] >= 0.f) != o0)) m |= 16u;
        if (bx && by      && ((sdf[v + 9506] >= 0.f) != o0)) m |= 32u;
        if (bx && by && bz&& ((sdf[v + 9507] >= 0.f) != o0)) m |= 64u;
        cnt = __popc(m);
        mask[v] = (uint8_t)m;
    }
    __shared__ uint32_t sh[1024];
    int t = threadIdx.x;
    sh[t] = cnt;
    __syncthreads();
    for (int o = 1; o < 1024; o <<= 1) {
        uint32_t x = (t >= o) ? sh[t - o] : 0;
        __syncthreads();
        sh[t] += x;
        __syncthreads();
    }
    if (v < NV3) vloc[v] = sh[t] - cnt;
    if (t == 1023) vsums[blockIdx.x] = sh[1023];
}

// K2: per cell: count 1-tri and 2-tri tets among its 6 tets; packed uint64 block scan
__global__ __launch_bounds__(1024) void k_cscan(const float* __restrict__ sdf,
                                                uint64_t* __restrict__ cloc,
                                                uint64_t* __restrict__ csums) {
    int c = blockIdx.x * 1024 + threadIdx.x;  // NCELL == CBLOCKS*1024 exactly
    int cx = c / (RES * RES);
    int r = c - cx * RES * RES;
    int cy = r / RES;
    int cz = r - cy * RES;
    int base = cx * N1SQ + cy * N1 + cz;
    uint32_t occ = 0;
#pragma unroll
    for (int b = 0; b < 8; b++)
        occ |= (sdf[base + corner_off(b)] >= 0.f) ? (1u << b) : 0u;
    uint32_t m1 = 0, m2 = 0;
#pragma unroll
    for (int k = 0; k < 6; k++) {
        int ti = ((occ >> d_six[k][0]) & 1) | (((occ >> d_six[k][1]) & 1) << 1) |
                 (((occ >> d_six[k][2]) & 1) << 2) | (((occ >> d_six[k][3]) & 1) << 3);
        int nt = d_ntri[ti];
        m1 += (nt == 1);
        m2 += (nt == 2);
    }
    uint64_t val = (uint64_t)m1 | ((uint64_t)m2 << 32);
    __shared__ uint64_t sh[1024];
    int t = threadIdx.x;
    sh[t] = val;
    __syncthreads();
    for (int o = 1; o < 1024; o <<= 1) {
        uint64_t x = (t >= o) ? sh[t - o] : 0;
        __syncthreads();
        sh[t] += x;
        __syncthreads();
    }
    cloc[c] = sh[t] - val;
    if (t == 1023) csums[blockIdx.x] = sh[1023];
}

// K3: single block: scan both block-sum arrays (exclusive), compute totals/offsets
__global__ __launch_bounds__(1024) void k_sums(uint32_t* __restrict__ vsums,
                                               uint64_t* __restrict__ csums,
                                               uint32_t* __restrict__ tot) {
    __shared__ uint32_t shv[1024];
    __shared__ uint64_t shc[1024];
    int t = threadIdx.x;
    uint32_t v = (t < VBLOCKS) ? vsums[t] : 0;
    uint64_t cv = (t < CBLOCKS) ? csums[t] : 0;
    shv[t] = v;
    shc[t] = cv;
    __syncthreads();
    for (int o = 1; o < 1024; o <<= 1) {
        uint32_t a = (t >= o) ? shv[t - o] : 0;
        uint64_t b = (t >= o) ? shc[t - o] : 0;
        __syncthreads();
        shv[t] += a;
        shc[t] += b;
        __syncthreads();
    }
    vsums[t] = shv[t] - v;
    csums[t] = shc[t] - cv;
    if (t == 1023) {
        uint32_t NV  = shv[1023];
        uint32_t NF1 = (uint32_t)(shc[1023] & 0xffffffffu);
        uint32_t NF2 = (uint32_t)(shc[1023] >> 32);
        uint32_t NF  = NF1 + 2u * NF2;
        tot[0] = NV;
        tot[1] = NF1;
        tot[2] = NF2;
        tot[3] = NV * 6u;                       // faces base (elements)
        tot[4] = NV * 6u + NF * 3u;             // uvs base
        tot[5] = NV * 6u + NF * 3u + UVFLOATS;  // uv_idx base
    }
}

// K4: emit interpolated vertices (6 features) for each crossing edge
__global__ __launch_bounds__(256) void k_verts(const float* __restrict__ sdf,
                                               const float* __restrict__ pos,
                                               const uint8_t* __restrict__ mask,
                                               const uint32_t* __restrict__ vloc,
                                               const uint32_t* __restrict__ vsums,
                                               float* __restrict__ out) {
    int v = blockIdx.x * 256 + threadIdx.x;
    if (v >= NV3) return;
    uint32_t m = mask[v];
    if (!m) return;
    uint32_t vid = vloc[v] + vsums[v >> 10];
    float sa = sdf[v];
    const float* pa = pos + (size_t)v * 6;
    const int diroff[7] = {1, 97, 98, 9409, 9410, 9506, 9507};
#pragma unroll
    for (int d = 0; d < 7; d++) {
        if (!((m >> d) & 1)) continue;
        int b = v + diroff[d];
        float sb = sdf[b];
        float denom = sa - sb;
        float w0 = -sb / denom;
        float w1 = sa / denom;
        const float* pb = pos + (size_t)b * 6;
        float* o = out + (size_t)vid * 6;
#pragma unroll
        for (int k = 0; k < 6; k++) o[k] = pa[k] * w0 + pb[k] * w1;
        vid++;
    }
}

// K5: emit faces (vertex ids as float) + uv_idx rows
__global__ __launch_bounds__(256) void k_faces(const float* __restrict__ sdf,
                                               const uint8_t* __restrict__ mask,
                                               const uint32_t* __restrict__ vloc,
                                               const uint32_t* __restrict__ vsums,
                                               const uint64_t* __restrict__ cloc,
                                               const uint64_t* __restrict__ csums,
                                               const uint32_t* __restrict__ tot,
                                               float* __restrict__ out) {
    int c = blockIdx.x * 256 + threadIdx.x;
    if (c >= NCELL) return;
    int cx = c / (RES * RES);
    int r = c - cx * RES * RES;
    int cy = r / RES;
    int cz = r - cy * RES;
    int base = cx * N1SQ + cy * N1 + cz;
    uint32_t occ = 0;
#pragma unroll
    for (int b = 0; b < 8; b++)
        occ |= (sdf[base + corner_off(b)] >= 0.f) ? (1u << b) : 0u;
    if (occ == 0u || occ == 255u) return;
    uint64_t pre = cloc[c] + csums[c >> 10];
    uint32_t r1 = (uint32_t)(pre & 0xffffffffu);
    uint32_t r2 = (uint32_t)(pre >> 32);
    uint32_t NF1 = tot[1];
    uint32_t fbase = tot[3];
    uint32_t ubase = tot[5];
#pragma unroll 1
    for (int k = 0; k < 6; k++) {
        int ti = ((occ >> d_six[k][0]) & 1) | (((occ >> d_six[k][1]) & 1) << 1) |
                 (((occ >> d_six[k][2]) & 1) << 2) | (((occ >> d_six[k][3]) & 1) << 3);
        int nt = d_ntri[ti];
        if (!nt) continue;
        uint32_t t_g = (uint32_t)c * 6u + (uint32_t)k;
        uint32_t row0;
        if (nt == 1) {
            row0 = r1;
            r1++;
        } else {
            row0 = NF1 + 2u * r2;
            r2++;
        }
        for (int tri = 0; tri < nt; tri++) {
            uint32_t rr = row0 + (uint32_t)tri;
            float* f = out + (size_t)fbase + (size_t)rr * 3;
            float* u = out + (size_t)ubase + (size_t)rr * 3;
#pragma unroll
            for (int j = 0; j < 3; j++) {
                int e = d_tt[ti][tri * 3 + j];
                int c0 = d_six[k][d_eb[e][0]];
                int c1 = d_six[k][d_eb[e][1]];
                int bl = c0 & c1;          // lower corner (bit-subset relation holds)
                int rank = (c0 ^ c1) - 1;  // direction rank 0..6
                int v0 = base + corner_off(bl);
                uint32_t vid = vloc[v0] + vsums[v0 >> 10] +
                               (uint32_t)__popc((uint32_t)mask[v0] & ((1u << rank) - 1u));
                f[j] = (float)vid;
            }
            u[0] = (float)(4u * t_g);
            u[1] = (float)(4u * t_g + (uint32_t)tri + 1u);
            u[2] = (float)(4u * t_g + (uint32_t)tri + 2u);
        }
    }
}

// K6: fill the (input-independent) uvs section
__global__ __launch_bounds__(256) void k_uvs(const uint32_t* __restrict__ tot,
                                             float* __restrict__ out) {
    int c = blockIdx.x * 256 + threadIdx.x;
    if (c >= UVCELLS) return;
    int i = c / UVN;
    int j = c - i * UVN;
    float x = (float)j * (1.0f / UVN);
    float y = (float)i * (1.0f / UVN);
    const float pad = 0.9f / UVN;
    float* o = out + (size_t)tot[4] + (size_t)c * 8;
    o[0] = x;
    o[1] = y;
    o[2] = x + pad;
    o[3] = y;
    o[4] = x + pad;
    o[5] = y + pad;
    o[6] = x;
    o[7] = y + pad;
}

extern "C" void kernel_launch(void* const* d_in, const int* in_sizes, int n_in,
                              void* d_out, int out_size, void* d_ws, size_t ws_size,
                              hipStream_t stream) {
    const float* pos = (const float*)d_in[0];
    const float* sdf = (const float*)d_in[1];
    // d_in[2] (tet_fx4) is deterministic from the grid; not needed.
    float* out = (float*)d_out;

    uint8_t* ws = (uint8_t*)d_ws;
    size_t off = 0;
    auto alloc = [&](size_t bytes) {
        void* p = ws + off;
        off = (off + bytes + 255) & ~(size_t)255;
        return p;
    };
    uint8_t*  mask  = (uint8_t*)alloc(NV3);
    uint32_t* vloc  = (uint32_t*)alloc((size_t)NV3 * 4);
    uint32_t* vsums = (uint32_t*)alloc(1024 * 4);
    uint64_t* cloc  = (uint64_t*)alloc((size_t)NCELL * 8);
    uint64_t* csums = (uint64_t*)alloc(1024 * 8);
    uint32_t* tot   = (uint32_t*)alloc(64);

    hipLaunchKernelGGL(k_vscan, dim3(VBLOCKS), dim3(1024), 0, stream, sdf, mask, vloc, vsums);
    hipLaunchKernelGGL(k_cscan, dim3(CBLOCKS), dim3(1024), 0, stream, sdf, cloc, csums);
    hipLaunchKernelGGL(k_sums, dim3(1), dim3(1024), 0, stream, vsums, csums, tot);
    hipLaunchKernelGGL(k_verts, dim3((NV3 + 255) / 256), dim3(256), 0, stream,
                       sdf, pos, mask, vloc, vsums, out);
    hipLaunchKernelGGL(k_faces, dim3((NCELL + 255) / 256), dim3(256), 0, stream,
                       sdf, mask, vloc, vsums, cloc, csums, tot, out);
    hipLaunchKernelGGL(k_uvs, dim3((UVCELLS + 255) / 256), dim3(256), 0, stream, tot, out);
}

// Round 2
// 88.809 us; speedup vs baseline: 1.1906x; 1.1906x over previous
//
#include <hip/hip_runtime.h>
#include <stdint.h>

#define N1     97
#define N1SQ   9409
#define NV3    912673      // 97^3 lattice vertices
#define RES    96
#define NCELL  884736      // 96^3 cells
#define VBLOCKS 892        // ceil(NV3/1024), vscan blocks (256 thr x 4/thread)
#define CBLOCKS 864        // NCELL/1024,    cscan blocks (256 thr x 4/thread)
#define UVN    2304
#define UVCELLS 5308416    // 2304^2
#define UVFLOATS 42467328  // UVCELLS*8

// phase2 geometry
#define VB2 3566           // ceil(NV3/256)
#define FB2 3456           // NCELL/256
#define NSPARSE (VB2 + FB2)        // 7022
#define UVB2 10368                 // ceil(ceil(UVFLOATS/4)/4/256) worst case
#define P2BLOCKS (2 * NSPARSE + (UVB2 - NSPARSE))  // 17390

__device__ __constant__ int d_tt[16][6] = {
    {-1,-1,-1,-1,-1,-1}, {1,0,2,-1,-1,-1}, {4,0,3,-1,-1,-1}, {1,4,2,1,3,4},
    {3,1,5,-1,-1,-1}, {2,3,0,2,5,3}, {1,4,0,1,5,4}, {4,2,5,-1,-1,-1},
    {4,5,2,-1,-1,-1}, {4,1,0,4,5,1}, {3,2,0,3,5,2}, {1,3,5,-1,-1,-1},
    {4,1,2,4,3,1}, {3,0,4,-1,-1,-1}, {2,0,1,-1,-1,-1}, {-1,-1,-1,-1,-1,-1}};
__device__ __constant__ int d_six[6][4] = {
    {0,5,1,7},{0,1,3,7},{0,3,2,7},{0,2,6,7},{0,6,4,7},{0,4,5,7}};
__device__ __constant__ int d_eb[6][2] = {{0,1},{0,2},{0,3},{1,2},{1,3},{2,3}};

__device__ __forceinline__ int corner_off(int b) {
    return (b >> 2) * N1SQ + ((b >> 1) & 1) * N1 + (b & 1);
}

// Phase 1 fused: blocks [0,VBLOCKS) do vertex masks+scan; [VBLOCKS, +CBLOCKS) do cell occ+scan.
// 256 threads, 4 elements/thread, wave-shuffle scan (1 barrier).
__global__ __launch_bounds__(256) void k_phase1(const float* __restrict__ sdf,
                                                uint8_t* __restrict__ mask,
                                                uint16_t* __restrict__ vloc,
                                                uint32_t* __restrict__ vsums,
                                                uint8_t* __restrict__ cocc,
                                                uint32_t* __restrict__ cloc,
                                                uint64_t* __restrict__ csums) {
    int bid = blockIdx.x;
    int t = threadIdx.x;
    int lane = t & 63, wid = t >> 6;
    __shared__ uint32_t wtot[4];

    if (bid < VBLOCKS) {
        int v0 = bid * 1024 + t * 4;
        uint32_t msks = 0;
        uint32_t cnts[4];
        uint32_t tsum = 0;
#pragma unroll
        for (int i = 0; i < 4; i++) {
            int v = v0 + i;
            uint32_t m = 0;
            if (v < NV3) {
                int x = v / N1SQ;
                int r = v - x * N1SQ;
                int y = r / N1;
                int z = r - y * N1;
                bool o0 = sdf[v] >= 0.f;
                bool bx = x < RES, by = y < RES, bz = z < RES;
                if (bz             && ((sdf[v + 1]    >= 0.f) != o0)) m |= 1u;
                if (by             && ((sdf[v + 97]   >= 0.f) != o0)) m |= 2u;
                if (by && bz       && ((sdf[v + 98]   >= 0.f) != o0)) m |= 4u;
                if (bx             && ((sdf[v + 9409] >= 0.f) != o0)) m |= 8u;
                if (bx && bz       && ((sdf[v + 9410] >= 0.f) != o0)) m |= 16u;
                if (bx && by       && ((sdf[v + 9506] >= 0.f) != o0)) m |= 32u;
                if (bx && by && bz && ((sdf[v + 9507] >= 0.f) != o0)) m |= 64u;
            }
            msks |= m << (8 * i);
            cnts[i] = __popc(m);
            tsum += cnts[i];
        }
        uint32_t incl = tsum;
#pragma unroll
        for (int d = 1; d < 64; d <<= 1) {
            uint32_t nv = __shfl_up(incl, d, 64);
            if (lane >= d) incl += nv;
        }
        if (lane == 63) wtot[wid] = incl;
        __syncthreads();
        uint32_t wpre = 0;
#pragma unroll
        for (int w = 0; w < 4; w++)
            if (w < wid) wpre += wtot[w];
        uint32_t base = wpre + incl - tsum;
        if (t == 0) vsums[bid] = wtot[0] + wtot[1] + wtot[2] + wtot[3];
        if (v0 + 4 <= NV3) {
            uchar4 mv = make_uchar4(msks & 0xff, (msks >> 8) & 0xff,
                                    (msks >> 16) & 0xff, msks >> 24);
            *(uchar4*)(mask + v0) = mv;
            ushort4 lv;
            lv.x = (uint16_t)base;
            lv.y = (uint16_t)(base + cnts[0]);
            lv.z = (uint16_t)(base + cnts[0] + cnts[1]);
            lv.w = (uint16_t)(base + cnts[0] + cnts[1] + cnts[2]);
            *(ushort4*)(vloc + v0) = lv;
        } else {
            uint32_t b = base;
            for (int i = 0; i < 4; i++) {
                int v = v0 + i;
                if (v < NV3) {
                    mask[v] = (uint8_t)((msks >> (8 * i)) & 0xff);
                    vloc[v] = (uint16_t)b;
                    b += cnts[i];
                }
            }
        }
    } else {
        int cb = bid - VBLOCKS;
        int c0 = cb * 1024 + t * 4;                 // cz0 % 4 == 0, never wraps a z-row
        int cx = c0 / (RES * RES);
        int r = c0 - cx * RES * RES;
        int cy = r / RES;
        int cz = r - cy * RES;
        int vb = cx * N1SQ + cy * N1 + cz;
        float r0[5], r1[5], r2[5], r3[5];
#pragma unroll
        for (int i = 0; i < 5; i++) {
            r0[i] = sdf[vb + i];
            r1[i] = sdf[vb + N1 + i];
            r2[i] = sdf[vb + N1SQ + i];
            r3[i] = sdf[vb + N1SQ + N1 + i];
        }
        uint32_t occ4 = 0;
        uint32_t pk[4];
        uint32_t tsum = 0;
#pragma unroll
        for (int i = 0; i < 4; i++) {
            uint32_t occ = (r0[i] >= 0.f ? 1u : 0u) | (r0[i + 1] >= 0.f ? 2u : 0u) |
                           (r1[i] >= 0.f ? 4u : 0u) | (r1[i + 1] >= 0.f ? 8u : 0u) |
                           (r2[i] >= 0.f ? 16u : 0u) | (r2[i + 1] >= 0.f ? 32u : 0u) |
                           (r3[i] >= 0.f ? 64u : 0u) | (r3[i + 1] >= 0.f ? 128u : 0u);
            occ4 |= occ << (8 * i);
            uint32_t m1 = 0, m2 = 0;
#pragma unroll
            for (int k = 0; k < 6; k++) {
                int ti = ((occ >> d_six[k][0]) & 1) | (((occ >> d_six[k][1]) & 1) << 1) |
                         (((occ >> d_six[k][2]) & 1) << 2) | (((occ >> d_six[k][3]) & 1) << 3);
                int pc = __popc((uint32_t)ti);
                m1 += (pc == 1) || (pc == 3);
                m2 += (pc == 2);
            }
            pk[i] = m1 | (m2 << 16);
            tsum += pk[i];
        }
        uint32_t incl = tsum;
#pragma unroll
        for (int d = 1; d < 64; d <<= 1) {
            uint32_t nv = __shfl_up(incl, d, 64);
            if (lane >= d) incl += nv;
        }
        if (lane == 63) wtot[wid] = incl;
        __syncthreads();
        uint32_t wpre = 0;
#pragma unroll
        for (int w = 0; w < 4; w++)
            if (w < wid) wpre += wtot[w];
        uint32_t base = wpre + incl - tsum;
        if (t == 0) {
            uint32_t bt = wtot[0] + wtot[1] + wtot[2] + wtot[3];
            csums[cb] = (uint64_t)(bt & 0xffffu) | ((uint64_t)(bt >> 16) << 32);
        }
        *(uchar4*)(cocc + c0) = make_uchar4(occ4 & 0xff, (occ4 >> 8) & 0xff,
                                            (occ4 >> 16) & 0xff, occ4 >> 24);
        uint4 cl;
        uint32_t run = base;
        cl.x = run; run += pk[0];
        cl.y = run; run += pk[1];
        cl.z = run; run += pk[2];
        cl.w = run;
        *(uint4*)(cloc + c0) = cl;
    }
}

// K-sums: single block scans both block-sum arrays (exclusive) + totals/offsets
__global__ __launch_bounds__(1024) void k_sums(uint32_t* __restrict__ vsums,
                                               uint64_t* __restrict__ csums,
                                               uint32_t* __restrict__ tot) {
    __shared__ uint32_t shv[1024];
    __shared__ uint64_t shc[1024];
    int t = threadIdx.x;
    uint32_t v = (t < VBLOCKS) ? vsums[t] : 0;
    uint64_t cv = (t < CBLOCKS) ? csums[t] : 0;
    shv[t] = v;
    shc[t] = cv;
    __syncthreads();
    for (int o = 1; o < 1024; o <<= 1) {
        uint32_t a = (t >= o) ? shv[t - o] : 0;
        uint64_t b = (t >= o) ? shc[t - o] : 0;
        __syncthreads();
        shv[t] += a;
        shc[t] += b;
        __syncthreads();
    }
    vsums[t] = shv[t] - v;
    csums[t] = shc[t] - cv;
    if (t == 1023) {
        uint32_t NV  = shv[1023];
        uint32_t NF1 = (uint32_t)(shc[1023] & 0xffffffffu);
        uint32_t NF2 = (uint32_t)(shc[1023] >> 32);
        uint32_t NF  = NF1 + 2u * NF2;
        tot[0] = NV;
        tot[1] = NF1;
        tot[2] = NF2;
        tot[3] = NV * 6u;
        tot[4] = NV * 6u + NF * 3u;
        tot[5] = NV * 6u + NF * 3u + UVFLOATS;
    }
}

__device__ __forceinline__ float uvval(uint32_t p) {
    uint32_t cell = p >> 3;
    uint32_t k = p & 7u;
    uint32_t i = cell / 2304u;          // compiler emits magic-mul
    uint32_t j = cell - i * 2304u;
    uint32_t idx = (k & 1u) ? i : j;    // odd k = y-type (row i), even k = x-type (col j)
    bool addpad = (k & 1u) ? (k >= 5u) : (k == 2u || k == 4u);
    return (float)idx * (1.0f / 2304.0f) + (addpad ? 0.9f / 2304.0f : 0.0f);
}

// Phase 2 fused: interleaved roles so BW-bound uvs writes overlap latency-bound
// verts/faces emission. bid<2*NSPARSE: odd=uvs, even=sparse; rest uvs.
__global__ __launch_bounds__(256) void k_phase2(const float* __restrict__ sdf,
                                                const float* __restrict__ pos,
                                                const uint8_t* __restrict__ mask,
                                                const uint16_t* __restrict__ vloc,
                                                const uint32_t* __restrict__ vsums,
                                                const uint8_t* __restrict__ cocc,
                                                const uint32_t* __restrict__ cloc,
                                                const uint64_t* __restrict__ csums,
                                                const uint32_t* __restrict__ tot,
                                                float* __restrict__ out) {
    int bid = blockIdx.x;
    int tid = threadIdx.x;
    int sparse = -1, uvb = -1;
    if (bid < 2 * NSPARSE) {
        if (bid & 1) uvb = bid >> 1;
        else sparse = bid >> 1;
    } else {
        uvb = NSPARSE + (bid - 2 * NSPARSE);
    }

    if (uvb >= 0) {
        // ---- uvs role: vectorized float4 writes with runtime alignment fixup ----
        uint32_t tot4 = tot[4];
        uint32_t A = (tot4 + 3u) & ~3u;
        uint32_t end = tot4 + UVFLOATS;
        uint32_t nvec = (end - A) >> 2;
#pragma unroll
        for (int r = 0; r < 4; r++) {
            uint32_t vi = (uint32_t)uvb * 1024u + (uint32_t)r * 256u + (uint32_t)tid;
            if (vi < nvec) {
                uint32_t e = A + vi * 4u;
                uint32_t p = e - tot4;
                float4 val;
                val.x = uvval(p);
                val.y = uvval(p + 1u);
                val.z = uvval(p + 2u);
                val.w = uvval(p + 3u);
                *(float4*)(out + e) = val;
            }
        }
        if (uvb == 0 && tid == 0) {
            for (uint32_t e = tot4; e < A; e++) out[e] = uvval(e - tot4);
            for (uint32_t e = A + nvec * 4u; e < end; e++) out[e] = uvval(e - tot4);
        }
        return;
    }

    if (sparse < VB2) {
        // ---- verts role ----
        int v = sparse * 256 + tid;
        if (v >= NV3) return;
        uint32_t m = mask[v];
        if (!m) return;
        uint32_t vid = (uint32_t)vloc[v] + vsums[v >> 10];
        float sa = sdf[v];
        const float* pa = pos + (size_t)v * 6;
        const int diroff[7] = {1, 97, 98, 9409, 9410, 9506, 9507};
#pragma unroll
        for (int d = 0; d < 7; d++) {
            if (!((m >> d) & 1)) continue;
            int b = v + diroff[d];
            float sb = sdf[b];
            float denom = sa - sb;
            float w0 = -sb / denom;
            float w1 = sa / denom;
            const float* pb = pos + (size_t)b * 6;
            float* o = out + (size_t)vid * 6;
#pragma unroll
            for (int k = 0; k < 6; k++) o[k] = pa[k] * w0 + pb[k] * w1;
            vid++;
        }
        return;
    }

    // ---- faces role ----
    {
        int c = (sparse - VB2) * 256 + tid;   // FB2*256 == NCELL exactly
        uint32_t occ = cocc[c];
        if (occ == 0u || occ == 255u) return;
        int cx = c / (RES * RES);
        int r = c - cx * RES * RES;
        int cy = r / RES;
        int cz = r - cy * RES;
        int base = cx * N1SQ + cy * N1 + cz;
        uint32_t cl = cloc[c];
        uint64_t cs = csums[c >> 10];
        uint32_t r1 = (uint32_t)(cs & 0xffffffffu) + (cl & 0xffffu);
        uint32_t r2 = (uint32_t)(cs >> 32) + (cl >> 16);
        uint32_t NF1 = tot[1];
        uint32_t fbase = tot[3];
        uint32_t ubase = tot[5];
#pragma unroll 1
        for (int k = 0; k < 6; k++) {
            int ti = ((occ >> d_six[k][0]) & 1) | (((occ >> d_six[k][1]) & 1) << 1) |
                     (((occ >> d_six[k][2]) & 1) << 2) | (((occ >> d_six[k][3]) & 1) << 3);
            int pc = __popc((uint32_t)ti);
            int nt = (pc == 2) ? 2 : ((pc == 1 || pc == 3) ? 1 : 0);
            if (!nt) continue;
            uint32_t t_g = (uint32_t)c * 6u + (uint32_t)k;
            uint32_t row0;
            if (nt == 1) {
                row0 = r1;
                r1++;
            } else {
                row0 = NF1 + 2u * r2;
                r2++;
            }
            for (int tri = 0; tri < nt; tri++) {
                uint32_t rr = row0 + (uint32_t)tri;
                float* f = out + (size_t)fbase + (size_t)rr * 3;
                float* u = out + (size_t)ubase + (size_t)rr * 3;
#pragma unroll
                for (int j = 0; j < 3; j++) {
                    int e = d_tt[ti][tri * 3 + j];
                    int c0 = d_six[k][d_eb[e][0]];
                    int c1 = d_six[k][d_eb[e][1]];
                    int bl = c0 & c1;
                    int rank = (c0 ^ c1) - 1;
                    int v0 = base + corner_off(bl);
                    uint32_t vid = (uint32_t)vloc[v0] + vsums[v0 >> 10] +
                                   (uint32_t)__popc((uint32_t)mask[v0] & ((1u << rank) - 1u));
                    f[j] = (float)vid;
                }
                u[0] = (float)(4u * t_g);
                u[1] = (float)(4u * t_g + (uint32_t)tri + 1u);
                u[2] = (float)(4u * t_g + (uint32_t)tri + 2u);
            }
        }
    }
}

extern "C" void kernel_launch(void* const* d_in, const int* in_sizes, int n_in,
                              void* d_out, int out_size, void* d_ws, size_t ws_size,
                              hipStream_t stream) {
    const float* pos = (const float*)d_in[0];
    const float* sdf = (const float*)d_in[1];
    float* out = (float*)d_out;

    uint8_t* ws = (uint8_t*)d_ws;
    size_t off = 0;
    auto alloc = [&](size_t bytes) {
        void* p = ws + off;
        off = (off + bytes + 255) & ~(size_t)255;
        return p;
    };
    uint8_t*  mask  = (uint8_t*)alloc(NV3);
    uint16_t* vloc  = (uint16_t*)alloc((size_t)NV3 * 2);
    uint32_t* vsums = (uint32_t*)alloc(1024 * 4);
    uint8_t*  cocc  = (uint8_t*)alloc(NCELL);
    uint32_t* cloc  = (uint32_t*)alloc((size_t)NCELL * 4);
    uint64_t* csums = (uint64_t*)alloc(1024 * 8);
    uint32_t* tot   = (uint32_t*)alloc(64);

    hipLaunchKernelGGL(k_phase1, dim3(VBLOCKS + CBLOCKS), dim3(256), 0, stream,
                       sdf, mask, vloc, vsums, cocc, cloc, csums);
    hipLaunchKernelGGL(k_sums, dim3(1), dim3(1024), 0, stream, vsums, csums, tot);
    hipLaunchKernelGGL(k_phase2, dim3(P2BLOCKS), dim3(256), 0, stream,
                       sdf, pos, mask, vloc, vsums, cocc, cloc, csums, tot, out);
}